// Round 1
// 494.083 us; speedup vs baseline: 1.0411x; 1.0411x over previous
//
#include <hip/hip_runtime.h>

// Problem constants (match reference)
constexpr int B_    = 4;
constexpr int V_    = 80000;
constexpr int P_    = 20;
constexpr int COUT  = 64;
constexpr int NX_   = 640;
constexpr int NY_   = 640;
constexpr int NYX   = NX_ * NY_;          // 409600 (divisible by 4)
constexpr float BEV = 100.0f;
constexpr float VXc = BEV / NX_;           // 0.15625
constexpr float VYc = BEV / NY_;
constexpr float XOFF = VXc * 0.5f - BEV * 0.5f;   // -49.921875
constexpr float YOFF = VYc * 0.5f - BEV * 0.5f;
constexpr float EPS  = 0.001f;

// Native vector type usable with __builtin_nontemporal_store
typedef float  vf4 __attribute__((ext_vector_type(4)));

// Pass 1: one wave (64 lanes) per pillar; lane = output channel.
// Algebraic collapse: feats.W = x*(w0+w4+w7) + y*(w1+w5+w8) + z*(w2+w6)
//                             + i*w3 + (bias - mean.w456 - center.w78)
// The mean enters only the constant term, so max over points commutes with
// it -> single fused loop.
// NEW: point loop unrolled by 4 with cndmask masking -> 4 independent loads
// in flight per chunk instead of a serial load->use chain per point.
// (p0 in {0,4,8,12,16} when p0 < n <= 20, so pv[p0+3] is always within the
// pillar's own 20-point row: no OOB.)
__global__ __launch_bounds__(256) void pillar_feat_kernel(
    const float* __restrict__ voxels,      // (V, P, 4)
    const int*   __restrict__ num_points,  // (V,)
    const int*   __restrict__ coors,       // (V, 4)  [b, 0, y, x]
    const float* __restrict__ W,           // (9, 64)
    const float* __restrict__ gamma_,      // (64,)
    const float* __restrict__ beta_,       // (64,)
    const float* __restrict__ rmean,       // (64,)
    const float* __restrict__ rvar,        // (64,)
    float* __restrict__ feat,              // (V, 64) out
    int*   __restrict__ idxmap,            // (B*NYX,) out (pre-cleared to -1)
    float* __restrict__ zrow)              // (64,) out: zeroed for scatter
{
    const int v = blockIdx.x * 4 + (threadIdx.x >> 6);   // pillar (wave-uniform)
    const int c = threadIdx.x & 63;                       // channel (lane)

    // zero the shared zero-row used by scatter's pointer-select gather
    if (blockIdx.x == 0 && threadIdx.x < COUT) zrow[threadIdx.x] = 0.0f;

    if (v >= V_) return;

    int n = num_points[v];
    n = n < 1 ? 1 : (n > P_ ? P_ : n);

    const int4 co = ((const int4*)coors)[v];
    const int cb = co.x, cyi = co.z, cxi = co.w;

    // Fold BN into weights/bias: h' = feats . (W*scale) + bias
    const float scale = gamma_[c] * rsqrtf(rvar[c] + EPS);
    const float bias  = beta_[c] - rmean[c] * scale;
    float w[9];
    #pragma unroll
    for (int i = 0; i < 9; ++i) w[i] = W[i * COUT + c] * scale;

    const float wcx = w[0] + w[4] + w[7];
    const float wcy = w[1] + w[5] + w[8];
    const float wcz = w[2] + w[6];
    const float wcw = w[3];

    const float4* __restrict__ pv =
        (const float4*)(voxels + (size_t)v * (P_ * 4));

    float sx = 0.f, sy = 0.f, sz = 0.f;
    float dmax = -3.4e38f;
    for (int p0 = 0; p0 < n; p0 += 4) {
        // 4 independent wave-uniform loads issued together
        float4 q0 = pv[p0];
        float4 q1 = pv[p0 + 1];
        float4 q2 = pv[p0 + 2];
        float4 q3 = pv[p0 + 3];
        #pragma unroll
        for (int j = 0; j < 4; ++j) {
            float4 q = (j == 0) ? q0 : (j == 1) ? q1 : (j == 2) ? q2 : q3;
            const bool ok = (p0 + j) < n;
            const float msk = ok ? 1.0f : 0.0f;
            sx = fmaf(q.x, msk, sx);
            sy = fmaf(q.y, msk, sy);
            sz = fmaf(q.z, msk, sz);
            float d = fmaf(q.x, wcx, fmaf(q.y, wcy, fmaf(q.z, wcz, q.w * wcw)));
            dmax = fmaxf(dmax, ok ? d : -3.4e38f);
        }
    }
    const float inv = 1.0f / (float)n;
    const float ccx = (float)cxi * VXc + XOFF;
    const float ccy = (float)cyi * VYc + YOFF;
    const float btot = bias - (sx * inv) * w[4] - (sy * inv) * w[5]
                            - (sz * inv) * w[6] - ccx * w[7] - ccy * w[8];

    float m = dmax + btot;
    // Invalid rows have all-zero features -> h = bias; they participate in max
    if (n < P_) m = fmaxf(m, bias);

    feat[(size_t)v * COUT + c] = fmaxf(m, 0.0f);   // relu after max (monotone)

    if (c == 0) idxmap[cb * NYX + cyi * NX_ + cxi] = v;
}

// Pass 2: gather. Each thread owns 4 consecutive x-cells x all 64 channels.
// idxmap IS pre-cleared to -1 now, so validity is just idx >= 0 (no coors
// verification gather). Empty cells point at zrow -> all 64 gather loads are
// unconditional (no exec-mask predication), fully pipelined; empty-cell loads
// broadcast from one hot L1 line.
__global__ __launch_bounds__(256) void scatter_kernel(
    const float* __restrict__ feat,     // (V, 64)
    const int*   __restrict__ idxmap,   // (B*NYX,) -1 = empty
    const float* __restrict__ zrow,     // (64,) zeros
    float* __restrict__ canvas,         // (B, 64, NY, NX)
    float* __restrict__ occ)            // (B, 1, NY, NX)
{
    const int t = blockIdx.x * blockDim.x + threadIdx.x;   // cell-group id
    if (t >= (B_ * NYX) / 4) return;

    const int4 id = ((const int4*)idxmap)[t];
    const int cell0 = t * 4;
    const int b   = cell0 / NYX;
    const int rem = cell0 - b * NYX;

    const float4* __restrict__ f4 = (const float4*)feat;   // (V, 16) float4
    const float4* __restrict__ z4 = (const float4*)zrow;   // 16 float4 of 0

    const float4* p0r = (id.x >= 0) ? (f4 + (size_t)id.x * 16) : z4;
    const float4* p1r = (id.y >= 0) ? (f4 + (size_t)id.y * 16) : z4;
    const float4* p2r = (id.z >= 0) ? (f4 + (size_t)id.z * 16) : z4;
    const float4* p3r = (id.w >= 0) ? (f4 + (size_t)id.w * 16) : z4;

    // occupancy plane (4 cells per store)
    vf4 o = { id.x >= 0 ? 1.f : 0.f,
              id.y >= 0 ? 1.f : 0.f,
              id.z >= 0 ? 1.f : 0.f,
              id.w >= 0 ? 1.f : 0.f };
    __builtin_nontemporal_store(o, (vf4*)(occ + cell0));

    const size_t base = (size_t)b * COUT * NYX + (size_t)rem;

    #pragma unroll
    for (int cg = 0; cg < 16; ++cg) {
        float4 a0 = p0r[cg];
        float4 a1 = p1r[cg];
        float4 a2 = p2r[cg];
        float4 a3 = p3r[cg];
        // transpose 4x4: s_k = channel (4*cg+k) values for the 4 cells
        vf4 s0 = { a0.x, a1.x, a2.x, a3.x };
        vf4 s1 = { a0.y, a1.y, a2.y, a3.y };
        vf4 s2 = { a0.z, a1.z, a2.z, a3.z };
        vf4 s3 = { a0.w, a1.w, a2.w, a3.w };
        float* p0 = canvas + base + (size_t)(4 * cg + 0) * NYX;
        __builtin_nontemporal_store(s0, (vf4*)p0);
        __builtin_nontemporal_store(s1, (vf4*)(p0 + NYX));
        __builtin_nontemporal_store(s2, (vf4*)(p0 + 2 * NYX));
        __builtin_nontemporal_store(s3, (vf4*)(p0 + 3 * NYX));
    }
}

extern "C" void kernel_launch(void* const* d_in, const int* in_sizes, int n_in,
                              void* d_out, int out_size, void* d_ws, size_t ws_size,
                              hipStream_t stream) {
    const float* voxels     = (const float*)d_in[0];
    const int*   num_points = (const int*)  d_in[1];
    const int*   coors      = (const int*)  d_in[2];
    const float* W          = (const float*)d_in[3];
    const float* gamma_     = (const float*)d_in[4];
    const float* beta_      = (const float*)d_in[5];
    const float* rmean      = (const float*)d_in[6];
    const float* rvar       = (const float*)d_in[7];

    float* canvas = (float*)d_out;                         // (B,64,NY,NX)
    float* occ    = (float*)d_out + (size_t)B_ * COUT * NYX;

    float* feat   = (float*)d_ws;                          // V*64 floats = 20.5 MB
    int*   idxmap = (int*)((char*)d_ws + (size_t)V_ * COUT * sizeof(float)); // 6.55 MB
    float* zrow   = (float*)((char*)d_ws + (size_t)V_ * COUT * sizeof(float)
                                         + (size_t)B_ * NYX * sizeof(int)); // 256 B

    // Clear idxmap to -1 (0xFF bytes). Stream-ordered, graph-capturable.
    hipMemsetAsync(idxmap, 0xFF, (size_t)B_ * NYX * sizeof(int), stream);

    pillar_feat_kernel<<<(V_ + 3) / 4, 256, 0, stream>>>(
        voxels, num_points, coors, W, gamma_, beta_, rmean, rvar, feat, idxmap, zrow);

    scatter_kernel<<<(B_ * NYX / 4 + 255) / 256, 256, 0, stream>>>(
        feat, idxmap, zrow, canvas, occ);
}